// Round 6
// baseline (339.965 us; speedup 1.0000x reference)
//
#include <hip/hip_runtime.h>
#include <hip/hip_bf16.h>
#include <math.h>

// Dims: x[8192,4096] A[128,4096] B[8,4096,16] Wr[8,4096] br[8] -> out[8192,4096]
// Fused v2: block = 16 tokens, 8 waves, FULL K per wave, N split across waves.
//   phase1: wave w computes S[:, w*16..w*16+16] = x * W1^T tile (wave 0 also router tile 8)
//           x staged in LDS per 512-col chunk (shared), W1 streamed from L2 (depth-2 pipeline)
//   softmax -> W2s[16][128] bf16 in LDS
//   phase2: wave w computes out[:, w*512..(w+1)*512] in 64-col chunks, LDS-bounce nt-stores
#define D_DIM 4096
#define O_DIM 4096

typedef __attribute__((ext_vector_type(8))) short short8;
typedef __attribute__((ext_vector_type(4))) float floatx4;

__device__ inline unsigned short f2bf(float f) {
    union { float f; unsigned u; } v; v.f = f;
    unsigned r = v.u + 0x7FFF + ((v.u >> 16) & 1);   // RNE
    return (unsigned short)(r >> 16);
}

// packed f32x2 -> bf16x2 (v_cvt_pk_bf16_f32, RNE)
__device__ inline unsigned cvt2(float lo, float hi) {
    __hip_bfloat162 h2 = __float22bfloat162_rn(make_float2(lo, hi));
    union { __hip_bfloat162 h; unsigned u; } c; c.h = h2;
    return c.u;
}

// ---------- merged prep: W1bf [144][4096] bf16 (A,Wr,zeros) + Btbf [4096][128] ----------
__global__ __launch_bounds__(256) void k0_prep(const float* __restrict__ A,
                                               const float* __restrict__ Wr,
                                               const float* __restrict__ B,
                                               unsigned short* __restrict__ W1bf,
                                               unsigned short* __restrict__ Btbf) {
    if (blockIdx.x < 576) {
        int e = (blockIdx.x * 256 + threadIdx.x) * 4;    // 144*4096 elems
        int row = e >> 12;
        int col = e & 4095;
        float4 v;
        if (row < 128)      v = *(const float4*)(A + (size_t)row * D_DIM + col);
        else if (row < 136) v = *(const float4*)(Wr + (size_t)(row - 128) * D_DIM + col);
        else                v = make_float4(0.f, 0.f, 0.f, 0.f);
        ushort4 o; o.x = f2bf(v.x); o.y = f2bf(v.y); o.z = f2bf(v.z); o.w = f2bf(v.w);
        *(ushort4*)(W1bf + e) = o;
    } else {
        int e = ((blockIdx.x - 576) * 256 + threadIdx.x) * 4;   // 4096*128 elems
        int o = e >> 7;
        int k = e & 127;
        int h = k >> 4;
        int r = k & 15;
        float4 v = *(const float4*)(B + (size_t)h * (O_DIM * 16) + (size_t)o * 16 + r);
        ushort4 w; w.x = f2bf(v.x); w.y = f2bf(v.y); w.z = f2bf(v.z); w.w = f2bf(v.w);
        *(ushort4*)(Btbf + e) = w;
    }
}

// ---------- fused v2 ----------
// grid = 512 blocks (16 tokens), block = 512 threads (8 waves).
// LDS: union{ Xs[16][520]+S[16][148] (26.1 KB) | bounce[8][16][68] (34.8 KB) } + W2s (4.3 KB)
//   = 39.2 KB -> 3-4 blocks/CU; launch_bounds(512,6) -> 24 waves/CU target.
__global__ __launch_bounds__(512, 6) void kf2_fused(const float* __restrict__ X,
                                                    const unsigned short* __restrict__ W1bf,
                                                    const unsigned short* __restrict__ Btbf,
                                                    const float* __restrict__ br,
                                                    float* __restrict__ out) {
    __shared__ union {
        struct {
            short Xs[16][520];      // 512 bf16 + 8 pad: row stride 1040B -> 2-way-free frag reads
            float S[16][148];       // final GEMM1 scores + softmax scales
        } p1;
        float bounce[8][16][68];    // phase-2 per-wave store bounce (64 + 4 pad)
    } sm;
    __shared__ unsigned short W2s[16][136];
    const int tid  = threadIdx.x;
    const int wave = tid >> 6;
    const int lane = tid & 63;
    const int lrow = lane & 15;
    const int quad = lane >> 4;
    const int m0   = blockIdx.x * 16;

    // ===== phase 1: full-K GEMM1, N-tile per wave =====
    floatx4 acc = (floatx4)(0.f);
    floatx4 acc8 = (floatx4)(0.f);                        // wave 0 only: router tile (rows 128..143)
    const unsigned short* wb  = W1bf + (size_t)(wave * 16 + lrow) * D_DIM + quad * 8;
    const unsigned short* wb8 = W1bf + (size_t)(128 + lrow) * D_DIM + quad * 8;

    for (int c = 0; c < 8; ++c) {                         // 8 K-chunks of 512
        const int k0 = c * 512;
        // stage x chunk: 16 rows x 512 fp32 -> bf16 LDS. 1024 units(32B) / 512 thr = 2 each
        #pragma unroll
        for (int i = 0; i < 2; ++i) {
            int e   = tid + i * 512;
            int row = e >> 6;                             // 64 units per row
            int col = (e & 63) * 8;
            const float* xp = X + (size_t)(m0 + row) * D_DIM + k0 + col;
            float4 v0 = *(const float4*)(xp);
            float4 v1 = *(const float4*)(xp + 4);
            union { unsigned u[4]; short8 s; } o;
            o.u[0] = cvt2(v0.x, v0.y); o.u[1] = cvt2(v0.z, v0.w);
            o.u[2] = cvt2(v1.x, v1.y); o.u[3] = cvt2(v1.z, v1.w);
            *(short8*)&sm.p1.Xs[row][col] = o.s;
        }
        __syncthreads();

        // compute: 16 k-steps, b depth-2 register pipeline from L2
        short8 b_cur  = *(const short8*)(wb  + k0);
        short8 b8_cur;
        if (wave == 0) b8_cur = *(const short8*)(wb8 + k0);
        #pragma unroll
        for (int ks = 0; ks < 16; ++ks) {
            short8 b_nxt, b8_nxt;
            if (ks < 15) {
                b_nxt = *(const short8*)(wb + k0 + (ks + 1) * 32);
                if (wave == 0) b8_nxt = *(const short8*)(wb8 + k0 + (ks + 1) * 32);
            }
            short8 a = *(const short8*)&sm.p1.Xs[lrow][ks * 32 + quad * 8];
            acc = __builtin_amdgcn_mfma_f32_16x16x32_bf16(a, b_cur, acc, 0, 0, 0);
            if (wave == 0)
                acc8 = __builtin_amdgcn_mfma_f32_16x16x32_bf16(a, b8_cur, acc8, 0, 0, 0);
            if (ks < 15) { b_cur = b_nxt; if (wave == 0) b8_cur = b8_nxt; }
        }
        __syncthreads();
    }

    // write S: token = quad*4+reg (C/D row), col = tile*16 + lrow (C/D col)
    #pragma unroll
    for (int reg = 0; reg < 4; ++reg) {
        sm.p1.S[quad * 4 + reg][wave * 16 + lrow] = acc[reg];
        if (wave == 0) sm.p1.S[quad * 4 + reg][128 + lrow] = acc8[reg];
    }
    __syncthreads();

    // ===== softmax (cols 128..135) -> per-head scale in cols 136..143 =====
    if (tid < 16) {
        float l[8]; float m = -1e30f;
        #pragma unroll
        for (int h = 0; h < 8; ++h) { l[h] = sm.p1.S[tid][128 + h] + br[h]; m = fmaxf(m, l[h]); }
        float s = 0.f;
        #pragma unroll
        for (int h = 0; h < 8; ++h) { l[h] = __expf(l[h] - m); s += l[h]; }
        float inv = 16.0f / s;                            // H * SCALING = 16
        #pragma unroll
        for (int h = 0; h < 8; ++h) sm.p1.S[tid][136 + h] = l[h] * inv;
    }
    __syncthreads();

    // ===== W2s bf16 [16][128] = low * per-head scale =====
    {
        int row = tid >> 5;                               // 512 thr x 4 elems = 2048 cells
        int c   = (tid & 31) * 4;
        float sc = sm.p1.S[row][136 + (c >> 4)];
        float4 v = *(const float4*)&sm.p1.S[row][c];
        ushort4 o;
        o.x = f2bf(v.x * sc); o.y = f2bf(v.y * sc);
        o.z = f2bf(v.z * sc); o.w = f2bf(v.w * sc);
        *(ushort4*)&W2s[row][c] = o;
    }
    __syncthreads();                                      // S dead; bounce may now alias it

    // ===== phase 2: out[16][wave*512 .. +512] in 8 chunks of 64 cols =====
    short8 afr[4];
    #pragma unroll
    for (int ks = 0; ks < 4; ++ks)
        afr[ks] = *(const short8*)&W2s[lrow][ks * 32 + quad * 8];

    const int nb = wave * 512;
    #pragma unroll 1
    for (int nc = 0; nc < 8; ++nc) {
        const int n0c = nb + nc * 64;
        const unsigned short* bbase = Btbf + (size_t)(n0c + lrow) * 128 + quad * 8;
        floatx4 acc2[4];
        #pragma unroll
        for (int n = 0; n < 4; ++n) acc2[n] = (floatx4)(0.f);

        #pragma unroll
        for (int ks = 0; ks < 4; ++ks) {
            short8 b2[4];
            #pragma unroll
            for (int n = 0; n < 4; ++n)
                b2[n] = *(const short8*)(bbase + (size_t)(n * 16) * 128 + ks * 32);
            #pragma unroll
            for (int n = 0; n < 4; ++n)
                acc2[n] = __builtin_amdgcn_mfma_f32_16x16x32_bf16(afr[ks], b2[n], acc2[n], 0, 0, 0);
        }

        // per-wave bounce (no barrier: region private to wave, in-wave LDS ordering)
        #pragma unroll
        for (int n = 0; n < 4; ++n)
            #pragma unroll
            for (int reg = 0; reg < 4; ++reg)
                sm.bounce[wave][quad * 4 + reg][n * 16 + lrow] = acc2[n][reg];

        #pragma unroll
        for (int i = 0; i < 4; ++i) {
            int idx = lane + i * 64;                      // 0..255
            int row = idx >> 4;                           // 16 float4 per row
            int u   = idx & 15;
            floatx4 v = *(const floatx4*)&sm.bounce[wave][row][u * 4];
            __builtin_nontemporal_store(v,
                (floatx4*)(out + (size_t)(m0 + row) * O_DIM + n0c + u * 4));
        }
    }
}

extern "C" void kernel_launch(void* const* d_in, const int* in_sizes, int n_in,
                              void* d_out, int out_size, void* d_ws, size_t ws_size,
                              hipStream_t stream) {
    const float* x  = (const float*)d_in[0];
    const float* A  = (const float*)d_in[1];
    const float* B  = (const float*)d_in[2];
    const float* Wr = (const float*)d_in[3];
    const float* br = (const float*)d_in[4];
    float* out = (float*)d_out;

    // ws layout: W1bf 144*4096 bf16 = 589824 ushort; Btbf 4096*128 bf16 = 524288 ushort (~2.2 MB)
    unsigned short* W1bf = (unsigned short*)d_ws;
    unsigned short* Btbf = W1bf + 589824;

    k0_prep<<<dim3(1088), dim3(256), 0, stream>>>(A, Wr, B, W1bf, Btbf);
    kf2_fused<<<dim3(512), dim3(512), 0, stream>>>(x, W1bf, Btbf, br, out);
}